// Round 7
// baseline (20905.226 us; speedup 1.0000x reference)
//
#include <hip/hip_runtime.h>
#include <hip/hip_bf16.h>

#define B_   64
#define S_   512
#define IN_  512
#define H_   1024
#define OUT_ 512
#define H3_  3072
#define TC_  32          // timesteps per chunk
#define TCL2 5
#define NCHUNK (S_ / TC_)
#define MC_  (B_ * TC_)  // 2048 rows per chunk
#define NROW (B_ * S_)

// scan decomposition: 256 blocks = 4 row-groups x 64 col-groups, 128 thr each
#define NBLK 256
#define NTHR 128
#define EXN  32768       // u32s per exchange buffer: 64cg x 4rg x 16rows x 8
#define STAGE_OFF 0      // 16 rows x 2048 B = 32768
#define HOWN_OFF  32768  // 16x17 f32
#define ZOWN_OFF  33920
#define SMEM_BYTES 35072

typedef float f32x4 __attribute__((ext_vector_type(4)));
typedef short bf16x8 __attribute__((ext_vector_type(8)));
typedef unsigned int u32;
typedef u32 u32x4 __attribute__((ext_vector_type(4)));

__device__ __forceinline__ u32 f2bf_bits(float v) {
  union { __hip_bfloat16 b; unsigned short s; } cv;
  cv.b = __float2bfloat16(v);
  return (u32)cv.s;
}

// agent-coherent (LLC-served) accessors for cross-XCD exchange
__device__ __forceinline__ void coh_st(u32* p, u32 v) {
  __hip_atomic_store(p, v, __ATOMIC_RELAXED, __HIP_MEMORY_SCOPE_AGENT);
}
__device__ __forceinline__ u32 coh_ld(const u32* p) {
  return __hip_atomic_load(p, __ATOMIC_RELAXED, __HIP_MEMORY_SCOPE_AGENT);
}

// wait until all 64 peer flags of this row-group reach target.
__device__ __forceinline__ void waitflags(const u32* f, int rgbase, u32 target) {
  while (true) {
    u32 v = coh_ld(f + rgbase + (threadIdx.x & 63));
    if (__all((int)(v >= target))) break;
    __builtin_amdgcn_s_sleep(1);
  }
  __builtin_amdgcn_sched_barrier(0);
}

// stage this rg's 16 rows (32KB) from slab-major exchange buffer into
// XOR-swizzled LDS. Coalesced LLC-coherent loads.
__device__ __forceinline__ void stage_ex(const u32* __restrict__ src, char* stage, int tid,
                                         int rg) {
  u32x4 v[16];
#pragma unroll
  for (int i = 0; i < 16; ++i) {
    int c4 = tid + i * NTHR;  // 0..2047 dwordx4 chunks
    int cgp = c4 >> 5;        // 32 chunks per cg' slab
    int s = c4 & 31;
    const u32* p = src + (((size_t)(cgp * 4 + rg) * 16 + (s >> 1)) * 8 + (s & 1) * 4);
    asm volatile("global_load_dwordx4 %0, %1, off sc0 sc1" : "=v"(v[i]) : "v"(p));
  }
  asm volatile("s_waitcnt vmcnt(0)" ::: "memory");
#pragma unroll
  for (int i = 0; i < 16; ++i) {
    int c4 = tid + i * NTHR;
    int cgp = c4 >> 5;
    int s = c4 & 31;
    int r = s >> 1;
    *(u32x4*)(stage + r * 2048 + (((cgp * 32 + (s & 1) * 16)) ^ ((r & 7) << 4))) = v[i];
  }
}

// ---------------------------------------------------------------------------
__global__ __launch_bounds__(256) void cast_f32_to_bf16(const float* __restrict__ in,
                                                        __hip_bfloat16* __restrict__ out,
                                                        int n4) {
  int i = blockIdx.x * 256 + threadIdx.x;
  if (i >= n4) return;
  float4 v = ((const float4*)in)[i];
  out[4 * i + 0] = __float2bfloat16(v.x);
  out[4 * i + 1] = __float2bfloat16(v.y);
  out[4 * i + 2] = __float2bfloat16(v.z);
  out[4 * i + 3] = __float2bfloat16(v.w);
}

__global__ __launch_bounds__(256) void gather_cast_x(const float* __restrict__ x,
                                                     __hip_bfloat16* __restrict__ out, int t0) {
  int i = blockIdx.x * 256 + threadIdx.x;
  int e = i * 4;
  int b = e >> 14;
  int rem = e & 16383;
  float4 v = *(const float4*)(x + (size_t)b * (S_ * IN_) + (size_t)t0 * IN_ + rem);
  out[e + 0] = __float2bfloat16(v.x);
  out[e + 1] = __float2bfloat16(v.y);
  out[e + 2] = __float2bfloat16(v.z);
  out[e + 3] = __float2bfloat16(v.w);
}

// ---------------------------------------------------------------------------
// C[M,N](f32) = A[M,K](bf16) @ B[N,K](bf16)^T + bias[N]
// ---------------------------------------------------------------------------
template <bool REMAP>
__global__ __launch_bounds__(256) void gemm_nt_bias(const __hip_bfloat16* __restrict__ A,
                                                    const __hip_bfloat16* __restrict__ Bm,
                                                    const float* __restrict__ bias,
                                                    float* __restrict__ C, int M, int N, int K,
                                                    int t0) {
  const int lane = threadIdx.x & 63;
  const int w = threadIdx.x >> 6;
  const int wr = w >> 1, wc = w & 1;
  const int row0 = blockIdx.y * 128 + wr * 64;
  const int col0 = blockIdx.x * 128 + wc * 64;
  const int kl = (lane >> 4) * 8;
  const int m16 = lane & 15;
  f32x4 acc[4][4] = {};
  for (int k0 = 0; k0 < K; k0 += 32) {
    bf16x8 a[4], b[4];
#pragma unroll
    for (int i = 0; i < 4; ++i)
      a[i] = *(const bf16x8*)(A + (size_t)(row0 + i * 16 + m16) * K + k0 + kl);
#pragma unroll
    for (int j = 0; j < 4; ++j)
      b[j] = *(const bf16x8*)(Bm + (size_t)(col0 + j * 16 + m16) * K + k0 + kl);
#pragma unroll
    for (int i = 0; i < 4; ++i)
#pragma unroll
      for (int j = 0; j < 4; ++j)
        acc[i][j] = __builtin_amdgcn_mfma_f32_16x16x32_bf16(a[i], b[j], acc[i][j], 0, 0, 0);
  }
  const int rsub = (lane >> 4) * 4;
#pragma unroll
  for (int i = 0; i < 4; ++i) {
    int row = row0 + i * 16 + rsub;
#pragma unroll
    for (int j = 0; j < 4; ++j) {
      int col = col0 + j * 16 + m16;
      float bv = bias[col];
#pragma unroll
      for (int r = 0; r < 4; ++r) {
        int rr = row + r;
        int crow = REMAP ? ((rr >> TCL2) * S_ + t0 + (rr & (TC_ - 1))) : rr;
        C[(size_t)crow * N + col] = acc[i][j][r] + bv;
      }
    }
  }
}

// ---------------------------------------------------------------------------
// GRU scan, flag-based dataflow pipeline (no grid barriers).
// 256 blocks (rg=bx>>6, cg=bx&63) x 128 thr (2 waves).
// Exchange: slab-major [cg][rg][16 rows][8 u32], double-buffered by t-parity.
// Producer: sc1 stores -> vmcnt(0) -> __syncthreads -> seq flag (single writer).
// Consumer: spin on 64 peer flags (coalesced + __all) -> stage -> compute.
// Phase A: wave0 z (LDS), wave1 r -> publish rh[t&1]; flagA = baseA+t+1.
// Phase B: wave0 g + h update -> publish h[t&1]; flagB = baseB+t+2.
// ---------------------------------------------------------------------------
__global__ __launch_bounds__(NTHR) void gru_scan_chunk(
    const float* __restrict__ xp, const float* __restrict__ h0, int layer, int t0,
    const __hip_bfloat16* __restrict__ Wh, float* __restrict__ h_f32,
    u32* __restrict__ hbuf, u32* __restrict__ rhbuf,
    __hip_bfloat16* __restrict__ y, float* __restrict__ hid_out,
    u32* __restrict__ flagA, u32* __restrict__ flagB, u32 baseA, u32 baseB) {
  extern __shared__ char smem[];
  char* stage = smem + STAGE_OFF;
  float* h_own = (float*)(smem + HOWN_OFF);  // [16][17]
  float* z_own = (float*)(smem + ZOWN_OFF);  // [16][17]

  const int tid = threadIdx.x;
  const int lane = tid & 63;
  const int w = tid >> 6;
  const int bx = blockIdx.x;
  const int rg = bx >> 6;
  const int cg = bx & 63;
  const int fid = bx;          // flag index
  const int rgbase = rg * 64;  // peer flag base
  const int m16 = lane & 15;
  const int kl = (lane >> 4) * 8;
  const int rsub = (lane >> 4) * 4;
  const int swzA = (m16 & 7) << 4;

  // ---- init: h_own; publish h(-1) into hbuf parity1 at t0==0 ----
  {
    int row = tid >> 3, pp = tid & 7;  // 16 rows x 8 pairs
    int col = cg * 16 + pp * 2;
    int grow = rg * 16 + row;
    float v0, v1;
    if (t0 == 0) {
      v0 = h0[((size_t)grow * 2 + layer) * H_ + col];
      v1 = h0[((size_t)grow * 2 + layer) * H_ + col + 1];
      coh_st(hbuf + EXN + (((size_t)(cg * 4 + rg) * 16 + row) * 8 + pp),
             f2bf_bits(v0) | (f2bf_bits(v1) << 16));
    } else {
      v0 = h_f32[grow * H_ + col];
      v1 = h_f32[grow * H_ + col + 1];
    }
    h_own[row * 17 + pp * 2] = v0;
    h_own[row * 17 + pp * 2 + 1] = v1;
  }
  asm volatile("s_waitcnt vmcnt(0)" ::: "memory");
  __syncthreads();
  if (tid == 0) coh_st(flagB + fid, baseB + 1);

  for (int t = 0; t < TC_; ++t) {
    const int par = t & 1;
    // ---- prefetch xp (independent of flags) ----
    const int colA = cg * 16 + m16 + ((w == 1) ? H_ : 0);
    float xpv[4], xpg[4];
#pragma unroll
    for (int j = 0; j < 4; ++j) {
      int grow = rg * 16 + rsub + j;
      xpv[j] = xp[((size_t)(grow * TC_ + t)) * H3_ + colA];
    }
    if (w == 0) {
#pragma unroll
      for (int j = 0; j < 4; ++j) {
        int grow = rg * 16 + rsub + j;
        xpg[j] = xp[((size_t)(grow * TC_ + t)) * H3_ + 2 * H_ + cg * 16 + m16];
      }
    }

    // ================= phase A =================
    waitflags(flagB, rgbase, baseB + 1 + t);  // h(t-1) published by all peers
    stage_ex(hbuf + (par ^ 1) * EXN, stage, tid, rg);
    __syncthreads();
    {
      f32x4 acc0 = {}, acc1 = {};
      const char* abase = stage + m16 * 2048;
      const __hip_bfloat16* Bb = Wh + (size_t)colA * H_;
#pragma unroll
      for (int k0 = 0; k0 < H_; k0 += 64) {
        bf16x8 a0 = *(const bf16x8*)(abase + (((k0 + kl) * 2) ^ swzA));
        bf16x8 a1 = *(const bf16x8*)(abase + (((k0 + 32 + kl) * 2) ^ swzA));
        bf16x8 b0 = *(const bf16x8*)(Bb + k0 + kl);
        bf16x8 b1 = *(const bf16x8*)(Bb + k0 + 32 + kl);
        acc0 = __builtin_amdgcn_mfma_f32_16x16x32_bf16(a0, b0, acc0, 0, 0, 0);
        acc1 = __builtin_amdgcn_mfma_f32_16x16x32_bf16(a1, b1, acc1, 0, 0, 0);
      }
      if (w == 0) {
#pragma unroll
        for (int j = 0; j < 4; ++j) {
          float pre = acc0[j] + acc1[j] + xpv[j];
          z_own[(rsub + j) * 17 + m16] = 1.f / (1.f + expf(-pre));
        }
      } else {
#pragma unroll
        for (int j = 0; j < 4; ++j) {
          int lr = rsub + j;
          float pre = acc0[j] + acc1[j] + xpv[j];
          float s = 1.f / (1.f + expf(-pre));
          float rh = s * h_own[lr * 17 + m16];
          u32 bits = f2bf_bits(rh);
          u32 pair = bits | (((u32)__shfl_down((int)bits, 1)) << 16);
          if ((m16 & 1) == 0)
            coh_st(rhbuf + par * EXN + (((size_t)(cg * 4 + rg) * 16 + lr) * 8 + (m16 >> 1)),
                   pair);
        }
        asm volatile("s_waitcnt vmcnt(0)" ::: "memory");
      }
    }
    __syncthreads();
    if (tid == 0) coh_st(flagA + fid, baseA + t + 1);

    // ================= phase B =================
    waitflags(flagA, rgbase, baseA + t + 1);  // rh(t) published by all peers
    stage_ex(rhbuf + par * EXN, stage, tid, rg);
    __syncthreads();
    if (w == 0) {
      f32x4 acc0 = {}, acc1 = {};
      const char* abase = stage + m16 * 2048;
      const __hip_bfloat16* Bb = Wh + (size_t)(2 * H_ + cg * 16 + m16) * H_;
#pragma unroll
      for (int k0 = 0; k0 < H_; k0 += 64) {
        bf16x8 a0 = *(const bf16x8*)(abase + (((k0 + kl) * 2) ^ swzA));
        bf16x8 a1 = *(const bf16x8*)(abase + (((k0 + 32 + kl) * 2) ^ swzA));
        bf16x8 b0 = *(const bf16x8*)(Bb + k0 + kl);
        bf16x8 b1 = *(const bf16x8*)(Bb + k0 + 32 + kl);
        acc0 = __builtin_amdgcn_mfma_f32_16x16x32_bf16(a0, b0, acc0, 0, 0, 0);
        acc1 = __builtin_amdgcn_mfma_f32_16x16x32_bf16(a1, b1, acc1, 0, 0, 0);
      }
#pragma unroll
      for (int j = 0; j < 4; ++j) {
        int lr = rsub + j;
        float pre = acc0[j] + acc1[j] + xpg[j];
        float gg = tanhf(pre);
        float zz = z_own[lr * 17 + m16];
        float hv = h_own[lr * 17 + m16];
        float hn = zz * hv + (1.f - zz) * gg;
        h_own[lr * 17 + m16] = hn;
        u32 bits = f2bf_bits(hn);
        u32 pair = bits | (((u32)__shfl_down((int)bits, 1)) << 16);
        if ((m16 & 1) == 0)
          coh_st(hbuf + par * EXN + (((size_t)(cg * 4 + rg) * 16 + lr) * 8 + (m16 >> 1)), pair);
        y[((size_t)((rg * 16 + lr) * TC_ + t)) * H_ + cg * 16 + m16] = __float2bfloat16(hn);
      }
      asm volatile("s_waitcnt vmcnt(0)" ::: "memory");
    }
    __syncthreads();
    if (tid == 0) coh_st(flagB + fid, baseB + t + 2);
  }

  // ---- persist h_own (post-B __syncthreads ordered wave0's LDS writes) ----
  {
    int row = tid >> 3, pp = tid & 7;
    int col = cg * 16 + pp * 2;
    int grow = rg * 16 + row;
    float v0 = h_own[row * 17 + pp * 2];
    float v1 = h_own[row * 17 + pp * 2 + 1];
    h_f32[grow * H_ + col] = v0;
    h_f32[grow * H_ + col + 1] = v1;
    if (t0 + TC_ == S_) {
      hid_out[((size_t)grow * 2 + layer) * H_ + col] = v0;
      hid_out[((size_t)grow * 2 + layer) * H_ + col + 1] = v1;
    }
  }
}

// ---------------------------------------------------------------------------
extern "C" void kernel_launch(void* const* d_in, const int* in_sizes, int n_in,
                              void* d_out, int out_size, void* d_ws, size_t ws_size,
                              hipStream_t stream) {
  const float* x   = (const float*)d_in[0];
  const float* h0  = (const float*)d_in[1];
  const float* Wx0 = (const float*)d_in[2];
  const float* Wh0 = (const float*)d_in[3];
  const float* bh0 = (const float*)d_in[4];
  const float* Wx1 = (const float*)d_in[5];
  const float* Wh1 = (const float*)d_in[6];
  const float* bh1 = (const float*)d_in[7];
  const float* Why = (const float*)d_in[8];
  const float* by  = (const float*)d_in[9];
  float* out = (float*)d_out;
  float* hid_out = out + (size_t)NROW * OUT_;

  hipFuncSetAttribute((const void*)gru_scan_chunk,
                      hipFuncAttributeMaxDynamicSharedMemorySize, SMEM_BYTES);

  char* ws = (char*)d_ws;
  size_t off = 0;
  auto alloc = [&](size_t bytes) {
    char* p = ws + off;
    off += (bytes + 255) & ~(size_t)255;
    return p;
  };
  __hip_bfloat16* wx0b = (__hip_bfloat16*)alloc((size_t)H3_ * IN_ * 2);
  __hip_bfloat16* wh0b = (__hip_bfloat16*)alloc((size_t)H3_ * H_ * 2);
  __hip_bfloat16* wx1b = (__hip_bfloat16*)alloc((size_t)H3_ * H_ * 2);
  __hip_bfloat16* wh1b = (__hip_bfloat16*)alloc((size_t)H3_ * H_ * 2);
  __hip_bfloat16* whyb = (__hip_bfloat16*)alloc((size_t)OUT_ * H_ * 2);
  float* h_f32_0 = (float*)alloc((size_t)B_ * H_ * 4);
  float* h_f32_1 = (float*)alloc((size_t)B_ * H_ * 4);
  u32* hbuf_0 = (u32*)alloc((size_t)2 * EXN * 4);
  u32* hbuf_1 = (u32*)alloc((size_t)2 * EXN * 4);
  u32* rhbuf  = (u32*)alloc((size_t)2 * EXN * 4);
  __hip_bfloat16* x_bfc = (__hip_bfloat16*)alloc((size_t)MC_ * IN_ * 2);
  __hip_bfloat16* y_c   = (__hip_bfloat16*)alloc((size_t)MC_ * H_ * 2);
  float* xp_c           = (float*)alloc((size_t)MC_ * H3_ * 4);
  u32* flags            = (u32*)alloc(4 * 256 * 4);
  (void)ws_size;

  hipMemsetAsync(flags, 0, 4 * 256 * 4, stream);

  auto cast = [&](const float* in, __hip_bfloat16* o, size_t n) {
    cast_f32_to_bf16<<<dim3((unsigned)((n / 4 + 255) / 256)), dim3(256), 0, stream>>>(in, o,
                                                                                     (int)(n / 4));
  };
  cast(Wx0, wx0b, (size_t)H3_ * IN_);
  cast(Wh0, wh0b, (size_t)H3_ * H_);
  cast(Wx1, wx1b, (size_t)H3_ * H_);
  cast(Wh1, wh1b, (size_t)H3_ * H_);
  cast(Why, whyb, (size_t)OUT_ * H_);

  // cooperative launch preferred (co-residency); deterministic fallback.
  auto launch_scan = [&](const float* xpp, const __hip_bfloat16* whb, float* hf, u32* hb,
                         u32* fA, u32* fB, int layer, int t0, u32 baseA, u32 baseB) {
    void* args[] = {(void*)&xpp, (void*)&h0,    (void*)&layer, (void*)&t0,
                    (void*)&whb, (void*)&hf,    (void*)&hb,    (void*)&rhbuf,
                    (void*)&y_c, (void*)&hid_out, (void*)&fA,  (void*)&fB,
                    (void*)&baseA, (void*)&baseB};
    hipError_t e = hipLaunchCooperativeKernel((void*)gru_scan_chunk, dim3(NBLK), dim3(NTHR), args,
                                              SMEM_BYTES, stream);
    if (e != hipSuccess) {
      (void)hipGetLastError();  // clear sticky error
      gru_scan_chunk<<<dim3(NBLK), dim3(NTHR), SMEM_BYTES, stream>>>(
          xpp, h0, layer, t0, whb, hf, hb, rhbuf, y_c, hid_out, fA, fB, baseA, baseB);
    }
  };

  for (int c = 0; c < NCHUNK; ++c) {
    int t0 = c * TC_;
    u32 baseA = (u32)c * TC_;
    u32 baseB = (u32)c * (TC_ + 1);
    gather_cast_x<<<dim3(MC_ * IN_ / 4 / 256), dim3(256), 0, stream>>>(x, x_bfc, t0);
    gemm_nt_bias<false><<<dim3(H3_ / 128, MC_ / 128), dim3(256), 0, stream>>>(
        x_bfc, wx0b, bh0, xp_c, MC_, H3_, IN_, 0);
    launch_scan(xp_c, wh0b, h_f32_0, hbuf_0, flags + 0, flags + 256, 0, t0, baseA, baseB);
    gemm_nt_bias<false><<<dim3(H3_ / 128, MC_ / 128), dim3(256), 0, stream>>>(
        y_c, wx1b, bh1, xp_c, MC_, H3_, H_, 0);
    launch_scan(xp_c, wh1b, h_f32_1, hbuf_1, flags + 512, flags + 768, 1, t0, baseA, baseB);
    gemm_nt_bias<true><<<dim3(OUT_ / 128, MC_ / 128), dim3(256), 0, stream>>>(
        y_c, whyb, by, out, MC_, OUT_, H_, t0);
  }
}

// Round 9
// 13954.936 us; speedup vs baseline: 1.4981x; 1.4981x over previous
//
#include <hip/hip_runtime.h>
#include <hip/hip_bf16.h>

#define B_   64
#define S_   512
#define IN_  512
#define H_   1024
#define OUT_ 512
#define H3_  3072
#define TC_  32          // timesteps per chunk
#define TCL2 5
#define NCHUNK (S_ / TC_)
#define MC_  (B_ * TC_)  // 2048 rows per chunk
#define NROW (B_ * S_)

// scan decomposition: 256 blocks = 4 row-groups x 64 col-groups, 128 thr each
#define NBLK 256
#define NTHR 128
#define EXN  32768       // u32s per exchange buffer: 64cg x 4rg x 16rows x 8
#define FPAD 16          // flag padding: one 64B cacheline per block
#define STAGE_OFF 0      // 16 rows x 2048 B = 32768
#define HOWN_OFF  32768  // 16x17 f32
#define ZOWN_OFF  33920
#define SMEM_BYTES 35072

typedef float f32x4 __attribute__((ext_vector_type(4)));
typedef short bf16x8 __attribute__((ext_vector_type(8)));
typedef unsigned int u32;
typedef u32 u32x4 __attribute__((ext_vector_type(4)));

__device__ __forceinline__ u32 f2bf_bits(float v) {
  union { __hip_bfloat16 b; unsigned short s; } cv;
  cv.b = __float2bfloat16(v);
  return (u32)cv.s;
}

// agent-coherent (LLC-served) accessors for cross-XCD exchange
__device__ __forceinline__ void coh_st(u32* p, u32 v) {
  __hip_atomic_store(p, v, __ATOMIC_RELAXED, __HIP_MEMORY_SCOPE_AGENT);
}
__device__ __forceinline__ u32 coh_ld(const u32* p) {
  return __hip_atomic_load(p, __ATOMIC_RELAXED, __HIP_MEMORY_SCOPE_AGENT);
}

// wait until all 64 peer flags of this row-group reach target.
// flags padded to one cacheline each; poll backoff to avoid LLC hot-lining.
__device__ __forceinline__ void waitflags(const u32* f, int rgbase, u32 target) {
  const u32* my = f + (size_t)(rgbase + (threadIdx.x & 63)) * FPAD;
  int it = 0;
  while (true) {
    u32 v = coh_ld(my);
    if (__all((int)(v >= target))) break;
    if (it < 2) {
      __builtin_amdgcn_s_sleep(2);
    } else {
      __builtin_amdgcn_s_sleep(16);
    }
    ++it;
  }
  __builtin_amdgcn_sched_barrier(0);
}

// stage this rg's 16 rows (32KB) from slab-major exchange buffer into
// XOR-swizzled LDS. Coalesced LLC-coherent loads.
__device__ __forceinline__ void stage_ex(const u32* __restrict__ src, char* stage, int tid,
                                         int rg) {
  u32x4 v[16];
#pragma unroll
  for (int i = 0; i < 16; ++i) {
    int c4 = tid + i * NTHR;  // 0..2047 dwordx4 chunks
    int cgp = c4 >> 5;        // 32 chunks per cg' slab
    int s = c4 & 31;
    const u32* p = src + (((size_t)(cgp * 4 + rg) * 16 + (s >> 1)) * 8 + (s & 1) * 4);
    asm volatile("global_load_dwordx4 %0, %1, off sc0 sc1" : "=v"(v[i]) : "v"(p));
  }
  asm volatile("s_waitcnt vmcnt(0)" ::: "memory");
#pragma unroll
  for (int i = 0; i < 16; ++i) {
    int c4 = tid + i * NTHR;
    int cgp = c4 >> 5;
    int s = c4 & 31;
    int r = s >> 1;
    *(u32x4*)(stage + r * 2048 + (((cgp * 32 + (s & 1) * 16)) ^ ((r & 7) << 4))) = v[i];
  }
}

// ---------------------------------------------------------------------------
__global__ __launch_bounds__(256) void cast_f32_to_bf16(const float* __restrict__ in,
                                                        __hip_bfloat16* __restrict__ out,
                                                        int n4) {
  int i = blockIdx.x * 256 + threadIdx.x;
  if (i >= n4) return;
  float4 v = ((const float4*)in)[i];
  out[4 * i + 0] = __float2bfloat16(v.x);
  out[4 * i + 1] = __float2bfloat16(v.y);
  out[4 * i + 2] = __float2bfloat16(v.z);
  out[4 * i + 3] = __float2bfloat16(v.w);
}

__global__ __launch_bounds__(256) void gather_cast_x(const float* __restrict__ x,
                                                     __hip_bfloat16* __restrict__ out, int t0) {
  int i = blockIdx.x * 256 + threadIdx.x;
  int e = i * 4;
  int b = e >> 14;
  int rem = e & 16383;
  float4 v = *(const float4*)(x + (size_t)b * (S_ * IN_) + (size_t)t0 * IN_ + rem);
  out[e + 0] = __float2bfloat16(v.x);
  out[e + 1] = __float2bfloat16(v.y);
  out[e + 2] = __float2bfloat16(v.z);
  out[e + 3] = __float2bfloat16(v.w);
}

// ---------------------------------------------------------------------------
// C[M,N](f32) = A[M,K](bf16) @ B[N,K](bf16)^T + bias[N]
// ---------------------------------------------------------------------------
template <bool REMAP>
__global__ __launch_bounds__(256) void gemm_nt_bias(const __hip_bfloat16* __restrict__ A,
                                                    const __hip_bfloat16* __restrict__ Bm,
                                                    const float* __restrict__ bias,
                                                    float* __restrict__ C, int M, int N, int K,
                                                    int t0) {
  const int lane = threadIdx.x & 63;
  const int w = threadIdx.x >> 6;
  const int wr = w >> 1, wc = w & 1;
  const int row0 = blockIdx.y * 128 + wr * 64;
  const int col0 = blockIdx.x * 128 + wc * 64;
  const int kl = (lane >> 4) * 8;
  const int m16 = lane & 15;
  f32x4 acc[4][4] = {};
  for (int k0 = 0; k0 < K; k0 += 32) {
    bf16x8 a[4], b[4];
#pragma unroll
    for (int i = 0; i < 4; ++i)
      a[i] = *(const bf16x8*)(A + (size_t)(row0 + i * 16 + m16) * K + k0 + kl);
#pragma unroll
    for (int j = 0; j < 4; ++j)
      b[j] = *(const bf16x8*)(Bm + (size_t)(col0 + j * 16 + m16) * K + k0 + kl);
#pragma unroll
    for (int i = 0; i < 4; ++i)
#pragma unroll
      for (int j = 0; j < 4; ++j)
        acc[i][j] = __builtin_amdgcn_mfma_f32_16x16x32_bf16(a[i], b[j], acc[i][j], 0, 0, 0);
  }
  const int rsub = (lane >> 4) * 4;
#pragma unroll
  for (int i = 0; i < 4; ++i) {
    int row = row0 + i * 16 + rsub;
#pragma unroll
    for (int j = 0; j < 4; ++j) {
      int col = col0 + j * 16 + m16;
      float bv = bias[col];
#pragma unroll
      for (int r = 0; r < 4; ++r) {
        int rr = row + r;
        int crow = REMAP ? ((rr >> TCL2) * S_ + t0 + (rr & (TC_ - 1))) : rr;
        C[(size_t)crow * N + col] = acc[i][j][r] + bv;
      }
    }
  }
}

// ---------------------------------------------------------------------------
// GRU scan, flag-based dataflow pipeline (no grid barriers).
// 256 blocks (rg=bx>>6, cg=bx&63) x 128 thr (2 waves).
// Exchange: slab-major [cg][rg][16 rows][8 u32], double-buffered by t-parity.
// Producer: sc1 stores -> vmcnt(0) -> __syncthreads -> seq flag (single
// writer, own cacheline). Consumer: spin on 64 peer flags with backoff.
// ---------------------------------------------------------------------------
__global__ __launch_bounds__(NTHR) void gru_scan_chunk(
    const float* __restrict__ xp, const float* __restrict__ h0, int layer, int t0,
    const __hip_bfloat16* __restrict__ Wh, float* __restrict__ h_f32,
    u32* __restrict__ hbuf, u32* __restrict__ rhbuf,
    __hip_bfloat16* __restrict__ y, float* __restrict__ hid_out,
    u32* __restrict__ flagA, u32* __restrict__ flagB, u32 baseA, u32 baseB) {
  extern __shared__ char smem[];
  char* stage = smem + STAGE_OFF;
  float* h_own = (float*)(smem + HOWN_OFF);  // [16][17]
  float* z_own = (float*)(smem + ZOWN_OFF);  // [16][17]

  const int tid = threadIdx.x;
  const int lane = tid & 63;
  const int w = tid >> 6;
  const int bx = blockIdx.x;
  const int rg = bx >> 6;
  const int cg = bx & 63;
  const int fid = bx;          // flag index (x FPAD)
  const int rgbase = rg * 64;  // peer flag base
  const int m16 = lane & 15;
  const int kl = (lane >> 4) * 8;
  const int rsub = (lane >> 4) * 4;
  const int swzA = (m16 & 7) << 4;

  // ---- init: h_own; publish h(-1) into hbuf parity1 at t0==0 ----
  {
    int row = tid >> 3, pp = tid & 7;  // 16 rows x 8 pairs
    int col = cg * 16 + pp * 2;
    int grow = rg * 16 + row;
    float v0, v1;
    if (t0 == 0) {
      v0 = h0[((size_t)grow * 2 + layer) * H_ + col];
      v1 = h0[((size_t)grow * 2 + layer) * H_ + col + 1];
      coh_st(hbuf + EXN + (((size_t)(cg * 4 + rg) * 16 + row) * 8 + pp),
             f2bf_bits(v0) | (f2bf_bits(v1) << 16));
    } else {
      v0 = h_f32[grow * H_ + col];
      v1 = h_f32[grow * H_ + col + 1];
    }
    h_own[row * 17 + pp * 2] = v0;
    h_own[row * 17 + pp * 2 + 1] = v1;
  }
  asm volatile("s_waitcnt vmcnt(0)" ::: "memory");
  __syncthreads();
  if (tid == 0) coh_st(flagB + (size_t)fid * FPAD, baseB + 1);

  for (int t = 0; t < TC_; ++t) {
    const int par = t & 1;
    // ---- prefetch xp (independent of flags) ----
    const int colA = cg * 16 + m16 + ((w == 1) ? H_ : 0);
    float xpv[4], xpg[4];
#pragma unroll
    for (int j = 0; j < 4; ++j) {
      int grow = rg * 16 + rsub + j;
      xpv[j] = xp[((size_t)(grow * TC_ + t)) * H3_ + colA];
    }
    if (w == 0) {
#pragma unroll
      for (int j = 0; j < 4; ++j) {
        int grow = rg * 16 + rsub + j;
        xpg[j] = xp[((size_t)(grow * TC_ + t)) * H3_ + 2 * H_ + cg * 16 + m16];
      }
    }

    // ================= phase A =================
    waitflags(flagB, rgbase, baseB + 1 + t);  // h(t-1) published by all peers
    stage_ex(hbuf + (par ^ 1) * EXN, stage, tid, rg);
    __syncthreads();
    {
      f32x4 acc0 = {}, acc1 = {};
      const char* abase = stage + m16 * 2048;
      const __hip_bfloat16* Bb = Wh + (size_t)colA * H_;
#pragma unroll
      for (int k0 = 0; k0 < H_; k0 += 64) {
        bf16x8 a0 = *(const bf16x8*)(abase + (((k0 + kl) * 2) ^ swzA));
        bf16x8 a1 = *(const bf16x8*)(abase + (((k0 + 32 + kl) * 2) ^ swzA));
        bf16x8 b0 = *(const bf16x8*)(Bb + k0 + kl);
        bf16x8 b1 = *(const bf16x8*)(Bb + k0 + 32 + kl);
        acc0 = __builtin_amdgcn_mfma_f32_16x16x32_bf16(a0, b0, acc0, 0, 0, 0);
        acc1 = __builtin_amdgcn_mfma_f32_16x16x32_bf16(a1, b1, acc1, 0, 0, 0);
      }
      if (w == 0) {
#pragma unroll
        for (int j = 0; j < 4; ++j) {
          float pre = acc0[j] + acc1[j] + xpv[j];
          z_own[(rsub + j) * 17 + m16] = 1.f / (1.f + expf(-pre));
        }
      } else {
#pragma unroll
        for (int j = 0; j < 4; ++j) {
          int lr = rsub + j;
          float pre = acc0[j] + acc1[j] + xpv[j];
          float s = 1.f / (1.f + expf(-pre));
          float rh = s * h_own[lr * 17 + m16];
          u32 bits = f2bf_bits(rh);
          u32 pair = bits | (((u32)__shfl_down((int)bits, 1)) << 16);
          if ((m16 & 1) == 0)
            coh_st(rhbuf + par * EXN + (((size_t)(cg * 4 + rg) * 16 + lr) * 8 + (m16 >> 1)),
                   pair);
        }
        asm volatile("s_waitcnt vmcnt(0)" ::: "memory");
      }
    }
    __syncthreads();
    if (tid == 0) coh_st(flagA + (size_t)fid * FPAD, baseA + t + 1);

    // ================= phase B =================
    waitflags(flagA, rgbase, baseA + t + 1);  // rh(t) published by all peers
    stage_ex(rhbuf + par * EXN, stage, tid, rg);
    __syncthreads();
    if (w == 0) {
      f32x4 acc0 = {}, acc1 = {};
      const char* abase = stage + m16 * 2048;
      const __hip_bfloat16* Bb = Wh + (size_t)(2 * H_ + cg * 16 + m16) * H_;
#pragma unroll
      for (int k0 = 0; k0 < H_; k0 += 64) {
        bf16x8 a0 = *(const bf16x8*)(abase + (((k0 + kl) * 2) ^ swzA));
        bf16x8 a1 = *(const bf16x8*)(abase + (((k0 + 32 + kl) * 2) ^ swzA));
        bf16x8 b0 = *(const bf16x8*)(Bb + k0 + kl);
        bf16x8 b1 = *(const bf16x8*)(Bb + k0 + 32 + kl);
        acc0 = __builtin_amdgcn_mfma_f32_16x16x32_bf16(a0, b0, acc0, 0, 0, 0);
        acc1 = __builtin_amdgcn_mfma_f32_16x16x32_bf16(a1, b1, acc1, 0, 0, 0);
      }
#pragma unroll
      for (int j = 0; j < 4; ++j) {
        int lr = rsub + j;
        float pre = acc0[j] + acc1[j] + xpg[j];
        float gg = tanhf(pre);
        float zz = z_own[lr * 17 + m16];
        float hv = h_own[lr * 17 + m16];
        float hn = zz * hv + (1.f - zz) * gg;
        h_own[lr * 17 + m16] = hn;
        u32 bits = f2bf_bits(hn);
        u32 pair = bits | (((u32)__shfl_down((int)bits, 1)) << 16);
        if ((m16 & 1) == 0)
          coh_st(hbuf + par * EXN + (((size_t)(cg * 4 + rg) * 16 + lr) * 8 + (m16 >> 1)), pair);
        y[((size_t)((rg * 16 + lr) * TC_ + t)) * H_ + cg * 16 + m16] = __float2bfloat16(hn);
      }
      asm volatile("s_waitcnt vmcnt(0)" ::: "memory");
    }
    __syncthreads();
    if (tid == 0) coh_st(flagB + (size_t)fid * FPAD, baseB + t + 2);
  }

  // ---- persist h_own (post-B __syncthreads ordered wave0's LDS writes) ----
  {
    int row = tid >> 3, pp = tid & 7;
    int col = cg * 16 + pp * 2;
    int grow = rg * 16 + row;
    float v0 = h_own[row * 17 + pp * 2];
    float v1 = h_own[row * 17 + pp * 2 + 1];
    h_f32[grow * H_ + col] = v0;
    h_f32[grow * H_ + col + 1] = v1;
    if (t0 + TC_ == S_) {
      hid_out[((size_t)grow * 2 + layer) * H_ + col] = v0;
      hid_out[((size_t)grow * 2 + layer) * H_ + col + 1] = v1;
    }
  }
}

// ---------------------------------------------------------------------------
extern "C" void kernel_launch(void* const* d_in, const int* in_sizes, int n_in,
                              void* d_out, int out_size, void* d_ws, size_t ws_size,
                              hipStream_t stream) {
  const float* x   = (const float*)d_in[0];
  const float* h0  = (const float*)d_in[1];
  const float* Wx0 = (const float*)d_in[2];
  const float* Wh0 = (const float*)d_in[3];
  const float* bh0 = (const float*)d_in[4];
  const float* Wx1 = (const float*)d_in[5];
  const float* Wh1 = (const float*)d_in[6];
  const float* bh1 = (const float*)d_in[7];
  const float* Why = (const float*)d_in[8];
  const float* by  = (const float*)d_in[9];
  float* out = (float*)d_out;
  float* hid_out = out + (size_t)NROW * OUT_;

  (void)hipFuncSetAttribute((const void*)gru_scan_chunk,
                            hipFuncAttributeMaxDynamicSharedMemorySize, SMEM_BYTES);

  char* ws = (char*)d_ws;
  size_t off = 0;
  auto alloc = [&](size_t bytes) {
    char* p = ws + off;
    off += (bytes + 255) & ~(size_t)255;
    return p;
  };
  __hip_bfloat16* wx0b = (__hip_bfloat16*)alloc((size_t)H3_ * IN_ * 2);
  __hip_bfloat16* wh0b = (__hip_bfloat16*)alloc((size_t)H3_ * H_ * 2);
  __hip_bfloat16* wx1b = (__hip_bfloat16*)alloc((size_t)H3_ * H_ * 2);
  __hip_bfloat16* wh1b = (__hip_bfloat16*)alloc((size_t)H3_ * H_ * 2);
  __hip_bfloat16* whyb = (__hip_bfloat16*)alloc((size_t)OUT_ * H_ * 2);
  float* h_f32_0 = (float*)alloc((size_t)B_ * H_ * 4);
  float* h_f32_1 = (float*)alloc((size_t)B_ * H_ * 4);
  u32* hbuf_0 = (u32*)alloc((size_t)2 * EXN * 4);
  u32* hbuf_1 = (u32*)alloc((size_t)2 * EXN * 4);
  u32* rhbuf  = (u32*)alloc((size_t)2 * EXN * 4);
  __hip_bfloat16* x_bfc = (__hip_bfloat16*)alloc((size_t)MC_ * IN_ * 2);
  __hip_bfloat16* y_c   = (__hip_bfloat16*)alloc((size_t)MC_ * H_ * 2);
  float* xp_c           = (float*)alloc((size_t)MC_ * H3_ * 4);
  u32* flags            = (u32*)alloc(4 * 256 * FPAD * 4);  // 64KB, 1 line/flag
  (void)ws_size;

  (void)hipMemsetAsync(flags, 0, 4 * 256 * FPAD * 4, stream);

  auto cast = [&](const float* in, __hip_bfloat16* o, size_t n) {
    cast_f32_to_bf16<<<dim3((unsigned)((n / 4 + 255) / 256)), dim3(256), 0, stream>>>(in, o,
                                                                                     (int)(n / 4));
  };
  cast(Wx0, wx0b, (size_t)H3_ * IN_);
  cast(Wh0, wh0b, (size_t)H3_ * H_);
  cast(Wx1, wx1b, (size_t)H3_ * H_);
  cast(Wh1, wh1b, (size_t)H3_ * H_);
  cast(Why, whyb, (size_t)OUT_ * H_);

  // cooperative launch preferred (co-residency); deterministic fallback.
  auto launch_scan = [&](const float* xpp, const __hip_bfloat16* whb, float* hf, u32* hb,
                         u32* fA, u32* fB, int layer, int t0, u32 baseA, u32 baseB) {
    void* args[] = {(void*)&xpp, (void*)&h0,    (void*)&layer, (void*)&t0,
                    (void*)&whb, (void*)&hf,    (void*)&hb,    (void*)&rhbuf,
                    (void*)&y_c, (void*)&hid_out, (void*)&fA,  (void*)&fB,
                    (void*)&baseA, (void*)&baseB};
    hipError_t e = hipLaunchCooperativeKernel((void*)gru_scan_chunk, dim3(NBLK), dim3(NTHR), args,
                                              SMEM_BYTES, stream);
    if (e != hipSuccess) {
      (void)hipGetLastError();  // clear sticky error
      gru_scan_chunk<<<dim3(NBLK), dim3(NTHR), SMEM_BYTES, stream>>>(
          xpp, h0, layer, t0, whb, hf, hb, rhbuf, y_c, hid_out, fA, fB, baseA, baseB);
    }
  };

  u32* fA0 = flags;
  u32* fB0 = flags + 256 * FPAD;
  u32* fA1 = flags + 512 * FPAD;
  u32* fB1 = flags + 768 * FPAD;

  for (int c = 0; c < NCHUNK; ++c) {
    int t0 = c * TC_;
    u32 baseA = (u32)c * TC_;
    u32 baseB = (u32)c * (TC_ + 1);
    gather_cast_x<<<dim3(MC_ * IN_ / 4 / 256), dim3(256), 0, stream>>>(x, x_bfc, t0);
    gemm_nt_bias<false><<<dim3(H3_ / 128, MC_ / 128), dim3(256), 0, stream>>>(
        x_bfc, wx0b, bh0, xp_c, MC_, H3_, IN_, 0);
    launch_scan(xp_c, wh0b, h_f32_0, hbuf_0, fA0, fB0, 0, t0, baseA, baseB);
    gemm_nt_bias<false><<<dim3(H3_ / 128, MC_ / 128), dim3(256), 0, stream>>>(
        y_c, wx1b, bh1, xp_c, MC_, H3_, H_, 0);
    launch_scan(xp_c, wh1b, h_f32_1, hbuf_1, fA1, fB1, 1, t0, baseA, baseB);
    gemm_nt_bias<true><<<dim3(OUT_ / 128, MC_ / 128), dim3(256), 0, stream>>>(
        y_c, whyb, by, out, MC_, OUT_, H_, t0);
  }
}

// Round 10
// 11053.165 us; speedup vs baseline: 1.8913x; 1.2625x over previous
//
#include <hip/hip_runtime.h>
#include <hip/hip_bf16.h>

#define B_   64
#define S_   512
#define IN_  512
#define H_   1024
#define OUT_ 512
#define H3_  3072
#define TC_  32          // timesteps per chunk
#define TCL2 5
#define NCHUNK (S_ / TC_)
#define MC_  (B_ * TC_)  // 2048 rows per chunk
#define NROW (B_ * S_)

// scan decomposition per chain: 256 blocks = 4 rg x 64 cg, 128 thr each.
// fused kernel: 512 blocks = 2 chains (layer pipeline).
#define NBLK 512
#define NTHR 128
#define EXN  32768       // u32s per exchange buffer: 64cg x 4rg x 16rows x 8
#define FPAD 16          // flag padding: one 64B cacheline per block
#define STAGE_OFF 0      // 16 rows x 2048 B = 32768
#define HOWN_OFF  32768  // 16x17 f32
#define ZOWN_OFF  33920
#define SMEM_BYTES 35072

typedef float f32x4 __attribute__((ext_vector_type(4)));
typedef short bf16x8 __attribute__((ext_vector_type(8)));
typedef unsigned int u32;
typedef u32 u32x4 __attribute__((ext_vector_type(4)));

struct ChainArgs {
  const float* xp;
  const __hip_bfloat16* Wh;
  float* hf;
  u32* hbuf;
  u32* rhbuf;
  u32* fA;
  u32* fB;
  __hip_bfloat16* y;
  u32 baseA, baseB;
  int t0;
  int layer;
  int active;
};

__device__ __forceinline__ u32 f2bf_bits(float v) {
  union { __hip_bfloat16 b; unsigned short s; } cv;
  cv.b = __float2bfloat16(v);
  return (u32)cv.s;
}

// agent-coherent (LLC-served) accessors for cross-XCD exchange
__device__ __forceinline__ void coh_st(u32* p, u32 v) {
  __hip_atomic_store(p, v, __ATOMIC_RELAXED, __HIP_MEMORY_SCOPE_AGENT);
}
__device__ __forceinline__ u32 coh_ld(const u32* p) {
  return __hip_atomic_load(p, __ATOMIC_RELAXED, __HIP_MEMORY_SCOPE_AGENT);
}

// wait until all 64 peer flags of this row-group reach target.
__device__ __forceinline__ void waitflags(const u32* f, int rgbase, u32 target) {
  const u32* my = f + (size_t)(rgbase + (threadIdx.x & 63)) * FPAD;
  int it = 0;
  while (true) {
    u32 v = coh_ld(my);
    if (__all((int)(v >= target))) break;
    if (it < 2) {
      __builtin_amdgcn_s_sleep(2);
    } else {
      __builtin_amdgcn_s_sleep(16);
    }
    ++it;
  }
  __builtin_amdgcn_sched_barrier(0);
}

// stage this rg's 16 rows (32KB) from slab-major exchange buffer into
// XOR-swizzled LDS. Coalesced LLC-coherent loads.
__device__ __forceinline__ void stage_ex(const u32* __restrict__ src, char* stage, int tid,
                                         int rg) {
  u32x4 v[16];
#pragma unroll
  for (int i = 0; i < 16; ++i) {
    int c4 = tid + i * NTHR;  // 0..2047 dwordx4 chunks
    int cgp = c4 >> 5;        // 32 chunks per cg' slab
    int s = c4 & 31;
    const u32* p = src + (((size_t)(cgp * 4 + rg) * 16 + (s >> 1)) * 8 + (s & 1) * 4);
    asm volatile("global_load_dwordx4 %0, %1, off sc0 sc1" : "=v"(v[i]) : "v"(p));
  }
  asm volatile("s_waitcnt vmcnt(0)" ::: "memory");
#pragma unroll
  for (int i = 0; i < 16; ++i) {
    int c4 = tid + i * NTHR;
    int cgp = c4 >> 5;
    int s = c4 & 31;
    int r = s >> 1;
    *(u32x4*)(stage + r * 2048 + (((cgp * 32 + (s & 1) * 16)) ^ ((r & 7) << 4))) = v[i];
  }
}

// ---------------------------------------------------------------------------
__global__ __launch_bounds__(256) void cast_f32_to_bf16(const float* __restrict__ in,
                                                        __hip_bfloat16* __restrict__ out,
                                                        int n4) {
  int i = blockIdx.x * 256 + threadIdx.x;
  if (i >= n4) return;
  float4 v = ((const float4*)in)[i];
  out[4 * i + 0] = __float2bfloat16(v.x);
  out[4 * i + 1] = __float2bfloat16(v.y);
  out[4 * i + 2] = __float2bfloat16(v.z);
  out[4 * i + 3] = __float2bfloat16(v.w);
}

__global__ __launch_bounds__(256) void gather_cast_x(const float* __restrict__ x,
                                                     __hip_bfloat16* __restrict__ out, int t0) {
  int i = blockIdx.x * 256 + threadIdx.x;
  int e = i * 4;
  int b = e >> 14;
  int rem = e & 16383;
  float4 v = *(const float4*)(x + (size_t)b * (S_ * IN_) + (size_t)t0 * IN_ + rem);
  out[e + 0] = __float2bfloat16(v.x);
  out[e + 1] = __float2bfloat16(v.y);
  out[e + 2] = __float2bfloat16(v.z);
  out[e + 3] = __float2bfloat16(v.w);
}

// ---------------------------------------------------------------------------
// C[M,N](f32) = A[M,K](bf16) @ B[N,K](bf16)^T + bias[N]
// ---------------------------------------------------------------------------
template <bool REMAP>
__global__ __launch_bounds__(256) void gemm_nt_bias(const __hip_bfloat16* __restrict__ A,
                                                    const __hip_bfloat16* __restrict__ Bm,
                                                    const float* __restrict__ bias,
                                                    float* __restrict__ C, int M, int N, int K,
                                                    int t0) {
  const int lane = threadIdx.x & 63;
  const int w = threadIdx.x >> 6;
  const int wr = w >> 1, wc = w & 1;
  const int row0 = blockIdx.y * 128 + wr * 64;
  const int col0 = blockIdx.x * 128 + wc * 64;
  const int kl = (lane >> 4) * 8;
  const int m16 = lane & 15;
  f32x4 acc[4][4] = {};
  for (int k0 = 0; k0 < K; k0 += 32) {
    bf16x8 a[4], b[4];
#pragma unroll
    for (int i = 0; i < 4; ++i)
      a[i] = *(const bf16x8*)(A + (size_t)(row0 + i * 16 + m16) * K + k0 + kl);
#pragma unroll
    for (int j = 0; j < 4; ++j)
      b[j] = *(const bf16x8*)(Bm + (size_t)(col0 + j * 16 + m16) * K + k0 + kl);
#pragma unroll
    for (int i = 0; i < 4; ++i)
#pragma unroll
      for (int j = 0; j < 4; ++j)
        acc[i][j] = __builtin_amdgcn_mfma_f32_16x16x32_bf16(a[i], b[j], acc[i][j], 0, 0, 0);
  }
  const int rsub = (lane >> 4) * 4;
#pragma unroll
  for (int i = 0; i < 4; ++i) {
    int row = row0 + i * 16 + rsub;
#pragma unroll
    for (int j = 0; j < 4; ++j) {
      int col = col0 + j * 16 + m16;
      float bv = bias[col];
#pragma unroll
      for (int r = 0; r < 4; ++r) {
        int rr = row + r;
        int crow = REMAP ? ((rr >> TCL2) * S_ + t0 + (rr & (TC_ - 1))) : rr;
        C[(size_t)crow * N + col] = acc[i][j][r] + bv;
      }
    }
  }
}

// ---------------------------------------------------------------------------
// One GRU chain (one layer, one chunk) on 256 blocks; round-9 protocol.
// ---------------------------------------------------------------------------
__device__ __forceinline__ void chain_scan(const ChainArgs& ca, const float* __restrict__ h0,
                                           float* __restrict__ hid_out, char* smem, int bx) {
  char* stage = smem + STAGE_OFF;
  float* h_own = (float*)(smem + HOWN_OFF);  // [16][17]
  float* z_own = (float*)(smem + ZOWN_OFF);  // [16][17]

  const int tid = threadIdx.x;
  const int lane = tid & 63;
  const int w = tid >> 6;
  const int rg = bx >> 6;
  const int cg = bx & 63;
  const int fid = bx;
  const int rgbase = rg * 64;
  const int m16 = lane & 15;
  const int kl = (lane >> 4) * 8;
  const int rsub = (lane >> 4) * 4;
  const int swzA = (m16 & 7) << 4;

  const float* xp = ca.xp;
  const __hip_bfloat16* Wh = ca.Wh;
  u32* hbuf = ca.hbuf;
  u32* rhbuf = ca.rhbuf;
  u32* flagA = ca.fA;
  u32* flagB = ca.fB;
  const u32 baseA = ca.baseA, baseB = ca.baseB;
  const int t0 = ca.t0, layer = ca.layer;

  // ---- init: h_own; publish h(-1) into hbuf parity1 at t0==0 ----
  {
    int row = tid >> 3, pp = tid & 7;  // 16 rows x 8 pairs
    int col = cg * 16 + pp * 2;
    int grow = rg * 16 + row;
    float v0, v1;
    if (t0 == 0) {
      v0 = h0[((size_t)grow * 2 + layer) * H_ + col];
      v1 = h0[((size_t)grow * 2 + layer) * H_ + col + 1];
      coh_st(hbuf + EXN + (((size_t)(cg * 4 + rg) * 16 + row) * 8 + pp),
             f2bf_bits(v0) | (f2bf_bits(v1) << 16));
    } else {
      v0 = ca.hf[grow * H_ + col];
      v1 = ca.hf[grow * H_ + col + 1];
    }
    h_own[row * 17 + pp * 2] = v0;
    h_own[row * 17 + pp * 2 + 1] = v1;
  }
  asm volatile("s_waitcnt vmcnt(0)" ::: "memory");
  __syncthreads();
  if (tid == 0) coh_st(flagB + (size_t)fid * FPAD, baseB + 1);

  for (int t = 0; t < TC_; ++t) {
    const int par = t & 1;
    const int colA = cg * 16 + m16 + ((w == 1) ? H_ : 0);
    float xpv[4], xpg[4];
#pragma unroll
    for (int j = 0; j < 4; ++j) {
      int grow = rg * 16 + rsub + j;
      xpv[j] = xp[((size_t)(grow * TC_ + t)) * H3_ + colA];
    }
    if (w == 0) {
#pragma unroll
      for (int j = 0; j < 4; ++j) {
        int grow = rg * 16 + rsub + j;
        xpg[j] = xp[((size_t)(grow * TC_ + t)) * H3_ + 2 * H_ + cg * 16 + m16];
      }
    }

    // ================= phase A =================
    waitflags(flagB, rgbase, baseB + 1 + t);
    stage_ex(hbuf + (par ^ 1) * EXN, stage, tid, rg);
    __syncthreads();
    {
      f32x4 acc0 = {}, acc1 = {};
      const char* abase = stage + m16 * 2048;
      const __hip_bfloat16* Bb = Wh + (size_t)colA * H_;
#pragma unroll
      for (int k0 = 0; k0 < H_; k0 += 64) {
        bf16x8 a0 = *(const bf16x8*)(abase + (((k0 + kl) * 2) ^ swzA));
        bf16x8 a1 = *(const bf16x8*)(abase + (((k0 + 32 + kl) * 2) ^ swzA));
        bf16x8 b0 = *(const bf16x8*)(Bb + k0 + kl);
        bf16x8 b1 = *(const bf16x8*)(Bb + k0 + 32 + kl);
        acc0 = __builtin_amdgcn_mfma_f32_16x16x32_bf16(a0, b0, acc0, 0, 0, 0);
        acc1 = __builtin_amdgcn_mfma_f32_16x16x32_bf16(a1, b1, acc1, 0, 0, 0);
      }
      if (w == 0) {
#pragma unroll
        for (int j = 0; j < 4; ++j) {
          float pre = acc0[j] + acc1[j] + xpv[j];
          z_own[(rsub + j) * 17 + m16] = 1.f / (1.f + expf(-pre));
        }
      } else {
#pragma unroll
        for (int j = 0; j < 4; ++j) {
          int lr = rsub + j;
          float pre = acc0[j] + acc1[j] + xpv[j];
          float s = 1.f / (1.f + expf(-pre));
          float rh = s * h_own[lr * 17 + m16];
          u32 bits = f2bf_bits(rh);
          u32 pair = bits | (((u32)__shfl_down((int)bits, 1)) << 16);
          if ((m16 & 1) == 0)
            coh_st(rhbuf + par * EXN + (((size_t)(cg * 4 + rg) * 16 + lr) * 8 + (m16 >> 1)),
                   pair);
        }
        asm volatile("s_waitcnt vmcnt(0)" ::: "memory");
      }
    }
    __syncthreads();
    if (tid == 0) coh_st(flagA + (size_t)fid * FPAD, baseA + t + 1);

    // ================= phase B =================
    waitflags(flagA, rgbase, baseA + t + 1);
    stage_ex(rhbuf + par * EXN, stage, tid, rg);
    __syncthreads();
    if (w == 0) {
      f32x4 acc0 = {}, acc1 = {};
      const char* abase = stage + m16 * 2048;
      const __hip_bfloat16* Bb = Wh + (size_t)(2 * H_ + cg * 16 + m16) * H_;
#pragma unroll
      for (int k0 = 0; k0 < H_; k0 += 64) {
        bf16x8 a0 = *(const bf16x8*)(abase + (((k0 + kl) * 2) ^ swzA));
        bf16x8 a1 = *(const bf16x8*)(abase + (((k0 + 32 + kl) * 2) ^ swzA));
        bf16x8 b0 = *(const bf16x8*)(Bb + k0 + kl);
        bf16x8 b1 = *(const bf16x8*)(Bb + k0 + 32 + kl);
        acc0 = __builtin_amdgcn_mfma_f32_16x16x32_bf16(a0, b0, acc0, 0, 0, 0);
        acc1 = __builtin_amdgcn_mfma_f32_16x16x32_bf16(a1, b1, acc1, 0, 0, 0);
      }
#pragma unroll
      for (int j = 0; j < 4; ++j) {
        int lr = rsub + j;
        float pre = acc0[j] + acc1[j] + xpg[j];
        float gg = tanhf(pre);
        float zz = z_own[lr * 17 + m16];
        float hv = h_own[lr * 17 + m16];
        float hn = zz * hv + (1.f - zz) * gg;
        h_own[lr * 17 + m16] = hn;
        u32 bits = f2bf_bits(hn);
        u32 pair = bits | (((u32)__shfl_down((int)bits, 1)) << 16);
        if ((m16 & 1) == 0)
          coh_st(hbuf + par * EXN + (((size_t)(cg * 4 + rg) * 16 + lr) * 8 + (m16 >> 1)), pair);
        ca.y[((size_t)((rg * 16 + lr) * TC_ + t)) * H_ + cg * 16 + m16] = __float2bfloat16(hn);
      }
      asm volatile("s_waitcnt vmcnt(0)" ::: "memory");
    }
    __syncthreads();
    if (tid == 0) coh_st(flagB + (size_t)fid * FPAD, baseB + t + 2);
  }

  // ---- persist h_own ----
  {
    int row = tid >> 3, pp = tid & 7;
    int col = cg * 16 + pp * 2;
    int grow = rg * 16 + row;
    float v0 = h_own[row * 17 + pp * 2];
    float v1 = h_own[row * 17 + pp * 2 + 1];
    ca.hf[grow * H_ + col] = v0;
    ca.hf[grow * H_ + col + 1] = v1;
    if (t0 + TC_ == S_) {
      hid_out[((size_t)grow * 2 + layer) * H_ + col] = v0;
      hid_out[((size_t)grow * 2 + layer) * H_ + col + 1] = v1;
    }
  }
}

// fused: blocks [0,256) run chain a0 (layer 0, chunk c);
//        blocks [256,512) run chain a1 (layer 1, chunk c-1).
__global__ __launch_bounds__(NTHR) void gru_scan_fused(ChainArgs a0, ChainArgs a1,
                                                       const float* __restrict__ h0,
                                                       float* __restrict__ hid_out) {
  extern __shared__ char smem[];
  if (blockIdx.x < 256) {
    if (!a0.active) return;
    chain_scan(a0, h0, hid_out, smem, blockIdx.x);
  } else {
    if (!a1.active) return;
    chain_scan(a1, h0, hid_out, smem, blockIdx.x - 256);
  }
}

// ---------------------------------------------------------------------------
extern "C" void kernel_launch(void* const* d_in, const int* in_sizes, int n_in,
                              void* d_out, int out_size, void* d_ws, size_t ws_size,
                              hipStream_t stream) {
  const float* x   = (const float*)d_in[0];
  const float* h0  = (const float*)d_in[1];
  const float* Wx0 = (const float*)d_in[2];
  const float* Wh0 = (const float*)d_in[3];
  const float* bh0 = (const float*)d_in[4];
  const float* Wx1 = (const float*)d_in[5];
  const float* Wh1 = (const float*)d_in[6];
  const float* bh1 = (const float*)d_in[7];
  const float* Why = (const float*)d_in[8];
  const float* by  = (const float*)d_in[9];
  float* out = (float*)d_out;
  float* hid_out = out + (size_t)NROW * OUT_;

  (void)hipFuncSetAttribute((const void*)gru_scan_fused,
                            hipFuncAttributeMaxDynamicSharedMemorySize, SMEM_BYTES);

  char* ws = (char*)d_ws;
  size_t off = 0;
  auto alloc = [&](size_t bytes) {
    char* p = ws + off;
    off += (bytes + 255) & ~(size_t)255;
    return p;
  };
  __hip_bfloat16* wx0b = (__hip_bfloat16*)alloc((size_t)H3_ * IN_ * 2);
  __hip_bfloat16* wh0b = (__hip_bfloat16*)alloc((size_t)H3_ * H_ * 2);
  __hip_bfloat16* wx1b = (__hip_bfloat16*)alloc((size_t)H3_ * H_ * 2);
  __hip_bfloat16* wh1b = (__hip_bfloat16*)alloc((size_t)H3_ * H_ * 2);
  __hip_bfloat16* whyb = (__hip_bfloat16*)alloc((size_t)OUT_ * H_ * 2);
  float* h_f32_0 = (float*)alloc((size_t)B_ * H_ * 4);
  float* h_f32_1 = (float*)alloc((size_t)B_ * H_ * 4);
  u32* hbuf_0  = (u32*)alloc((size_t)2 * EXN * 4);
  u32* hbuf_1  = (u32*)alloc((size_t)2 * EXN * 4);
  u32* rhbuf_0 = (u32*)alloc((size_t)2 * EXN * 4);
  u32* rhbuf_1 = (u32*)alloc((size_t)2 * EXN * 4);
  __hip_bfloat16* x_bfc = (__hip_bfloat16*)alloc((size_t)MC_ * IN_ * 2);
  __hip_bfloat16* y0buf = (__hip_bfloat16*)alloc((size_t)MC_ * H_ * 2);
  __hip_bfloat16* y1buf = (__hip_bfloat16*)alloc((size_t)MC_ * H_ * 2);
  float* xp0buf = (float*)alloc((size_t)MC_ * H3_ * 4);
  float* xp1buf = (float*)alloc((size_t)MC_ * H3_ * 4);
  u32* flags    = (u32*)alloc(4 * 256 * FPAD * 4);  // 64KB, 1 line/flag
  (void)ws_size;

  (void)hipMemsetAsync(flags, 0, 4 * 256 * FPAD * 4, stream);

  auto cast = [&](const float* in, __hip_bfloat16* o, size_t n) {
    cast_f32_to_bf16<<<dim3((unsigned)((n / 4 + 255) / 256)), dim3(256), 0, stream>>>(in, o,
                                                                                     (int)(n / 4));
  };
  cast(Wx0, wx0b, (size_t)H3_ * IN_);
  cast(Wh0, wh0b, (size_t)H3_ * H_);
  cast(Wx1, wx1b, (size_t)H3_ * H_);
  cast(Wh1, wh1b, (size_t)H3_ * H_);
  cast(Why, whyb, (size_t)OUT_ * H_);

  u32* fA0 = flags;
  u32* fB0 = flags + 256 * FPAD;
  u32* fA1 = flags + 512 * FPAD;
  u32* fB1 = flags + 768 * FPAD;

  auto mkchain = [&](int layer, int chunk, int active) {
    ChainArgs ca;
    int cc = chunk < 0 ? 0 : chunk;
    ca.xp = layer == 0 ? xp0buf : xp1buf;
    ca.Wh = layer == 0 ? wh0b : wh1b;
    ca.hf = layer == 0 ? h_f32_0 : h_f32_1;
    ca.hbuf = layer == 0 ? hbuf_0 : hbuf_1;
    ca.rhbuf = layer == 0 ? rhbuf_0 : rhbuf_1;
    ca.fA = layer == 0 ? fA0 : fA1;
    ca.fB = layer == 0 ? fB0 : fB1;
    ca.y = layer == 0 ? y0buf : y1buf;
    ca.baseA = (u32)cc * TC_;
    ca.baseB = (u32)cc * (TC_ + 1);
    ca.t0 = cc * TC_;
    ca.layer = layer;
    ca.active = active;
    return ca;
  };

  // prologue
  gather_cast_x<<<dim3(MC_ * IN_ / 4 / 256), dim3(256), 0, stream>>>(x, x_bfc, 0);
  gemm_nt_bias<false><<<dim3(H3_ / 128, MC_ / 128), dim3(256), 0, stream>>>(
      x_bfc, wx0b, bh0, xp0buf, MC_, H3_, IN_, 0);

  for (int c = 0; c <= NCHUNK; ++c) {
    ChainArgs a0 = mkchain(0, c, c < NCHUNK ? 1 : 0);
    ChainArgs a1 = mkchain(1, c - 1, c > 0 ? 1 : 0);
    {
      void* args[] = {(void*)&a0, (void*)&a1, (void*)&h0, (void*)&hid_out};
      hipError_t e = hipLaunchCooperativeKernel((void*)gru_scan_fused, dim3(NBLK), dim3(NTHR),
                                                args, SMEM_BYTES, stream);
      if (e != hipSuccess) {
        (void)hipGetLastError();  // clear sticky error
        gru_scan_fused<<<dim3(NBLK), dim3(NTHR), SMEM_BYTES, stream>>>(a0, a1, h0, hid_out);
      }
    }
    if (c < NCHUNK) {
      // xp1 for layer-1 chunk c (consumed by fused(c+1))
      gemm_nt_bias<false><<<dim3(H3_ / 128, MC_ / 128), dim3(256), 0, stream>>>(
          y0buf, wx1b, bh1, xp1buf, MC_, H3_, H_, 0);
    }
    if (c + 1 < NCHUNK) {
      // xp0 for layer-0 chunk c+1 (consumed by fused(c+1))
      gather_cast_x<<<dim3(MC_ * IN_ / 4 / 256), dim3(256), 0, stream>>>(x, x_bfc, (c + 1) * TC_);
      gemm_nt_bias<false><<<dim3(H3_ / 128, MC_ / 128), dim3(256), 0, stream>>>(
          x_bfc, wx0b, bh0, xp0buf, MC_, H3_, IN_, 0);
    }
    if (c > 0) {
      // output projection for layer-1 chunk c-1 (y1buf just produced)
      gemm_nt_bias<true><<<dim3(OUT_ / 128, MC_ / 128), dim3(256), 0, stream>>>(
          y1buf, whyb, by, out, MC_, OUT_, H_, (c - 1) * TC_);
    }
  }
}

// Round 11
// 10585.656 us; speedup vs baseline: 1.9749x; 1.0442x over previous
//
#include <hip/hip_runtime.h>
#include <hip/hip_bf16.h>

#define B_   64
#define S_   512
#define IN_  512
#define H_   1024
#define OUT_ 512
#define H3_  3072
#define TC_  32          // timesteps per chunk
#define TCL2 5
#define NCHUNK (S_ / TC_)
#define MC_  (B_ * TC_)  // 2048 rows per chunk
#define NROW (B_ * S_)

// scan decomposition per chain: 256 blocks = 4 rg x 64 cg, 128 thr each.
// fused kernel: 512 blocks = 2 chains (layer pipeline).
#define NBLK 512
#define NTHR 128
#define EXN  32768       // u32s per exchange buffer: 64cg x 4rg x 16rows x 8
#define FPAD 16          // flag padding: one 64B cacheline per block
#define STAGE_OFF 0      // 16 rows x 2048 B = 32768
#define HOWN_OFF  32768  // 16x17 f32
#define ZOWN_OFF  33920
#define SMEM_BYTES 35072

typedef float f32x4 __attribute__((ext_vector_type(4)));
typedef short bf16x8 __attribute__((ext_vector_type(8)));
typedef unsigned int u32;
typedef u32 u32x4 __attribute__((ext_vector_type(4)));

struct ChainArgs {
  const float* xp;
  const __hip_bfloat16* Wh;
  float* hf;
  u32* hbuf;
  u32* rhbuf;
  u32* fA;
  u32* fB;
  __hip_bfloat16* y;
  u32 baseA, baseB;
  int t0;
  int layer;
  int active;
  int stagger;  // anti-phase delay iterations at dispatch start
};

__device__ __forceinline__ u32 f2bf_bits(float v) {
  union { __hip_bfloat16 b; unsigned short s; } cv;
  cv.b = __float2bfloat16(v);
  return (u32)cv.s;
}

// agent-coherent (LLC-served) accessors for cross-XCD exchange
__device__ __forceinline__ void coh_st(u32* p, u32 v) {
  __hip_atomic_store(p, v, __ATOMIC_RELAXED, __HIP_MEMORY_SCOPE_AGENT);
}
__device__ __forceinline__ u32 coh_ld(const u32* p) {
  return __hip_atomic_load(p, __ATOMIC_RELAXED, __HIP_MEMORY_SCOPE_AGENT);
}

// wait until all 64 peer flags of this row-group reach target.
__device__ __forceinline__ void waitflags(const u32* f, int rgbase, u32 target) {
  const u32* my = f + (size_t)(rgbase + (threadIdx.x & 63)) * FPAD;
  int it = 0;
  while (true) {
    u32 v = coh_ld(my);
    if (__all((int)(v >= target))) break;
    if (it < 2) {
      __builtin_amdgcn_s_sleep(2);
    } else {
      __builtin_amdgcn_s_sleep(8);
    }
    ++it;
  }
  __builtin_amdgcn_sched_barrier(0);
}

// stage this rg's 16 rows (32KB) from slab-major exchange buffer into
// XOR-swizzled LDS. Coalesced LLC-coherent loads.
__device__ __forceinline__ void stage_ex(const u32* __restrict__ src, char* stage, int tid,
                                         int rg) {
  u32x4 v[16];
#pragma unroll
  for (int i = 0; i < 16; ++i) {
    int c4 = tid + i * NTHR;  // 0..2047 dwordx4 chunks
    int cgp = c4 >> 5;        // 32 chunks per cg' slab
    int s = c4 & 31;
    const u32* p = src + (((size_t)(cgp * 4 + rg) * 16 + (s >> 1)) * 8 + (s & 1) * 4);
    asm volatile("global_load_dwordx4 %0, %1, off sc0 sc1" : "=v"(v[i]) : "v"(p));
  }
  asm volatile("s_waitcnt vmcnt(0)" ::: "memory");
#pragma unroll
  for (int i = 0; i < 16; ++i) {
    int c4 = tid + i * NTHR;
    int cgp = c4 >> 5;
    int s = c4 & 31;
    int r = s >> 1;
    *(u32x4*)(stage + r * 2048 + (((cgp * 32 + (s & 1) * 16)) ^ ((r & 7) << 4))) = v[i];
  }
}

// ---------------------------------------------------------------------------
__global__ __launch_bounds__(256) void cast_f32_to_bf16(const float* __restrict__ in,
                                                        __hip_bfloat16* __restrict__ out,
                                                        int n4) {
  int i = blockIdx.x * 256 + threadIdx.x;
  if (i >= n4) return;
  float4 v = ((const float4*)in)[i];
  out[4 * i + 0] = __float2bfloat16(v.x);
  out[4 * i + 1] = __float2bfloat16(v.y);
  out[4 * i + 2] = __float2bfloat16(v.z);
  out[4 * i + 3] = __float2bfloat16(v.w);
}

__global__ __launch_bounds__(256) void gather_cast_x(const float* __restrict__ x,
                                                     __hip_bfloat16* __restrict__ out, int t0) {
  int i = blockIdx.x * 256 + threadIdx.x;
  int e = i * 4;
  int b = e >> 14;
  int rem = e & 16383;
  float4 v = *(const float4*)(x + (size_t)b * (S_ * IN_) + (size_t)t0 * IN_ + rem);
  out[e + 0] = __float2bfloat16(v.x);
  out[e + 1] = __float2bfloat16(v.y);
  out[e + 2] = __float2bfloat16(v.z);
  out[e + 3] = __float2bfloat16(v.w);
}

// ---------------------------------------------------------------------------
// C[M,N](f32) = A[M,K](bf16) @ B[N,K](bf16)^T + bias[N]
// ---------------------------------------------------------------------------
template <bool REMAP>
__global__ __launch_bounds__(256) void gemm_nt_bias(const __hip_bfloat16* __restrict__ A,
                                                    const __hip_bfloat16* __restrict__ Bm,
                                                    const float* __restrict__ bias,
                                                    float* __restrict__ C, int M, int N, int K,
                                                    int t0) {
  const int lane = threadIdx.x & 63;
  const int w = threadIdx.x >> 6;
  const int wr = w >> 1, wc = w & 1;
  const int row0 = blockIdx.y * 128 + wr * 64;
  const int col0 = blockIdx.x * 128 + wc * 64;
  const int kl = (lane >> 4) * 8;
  const int m16 = lane & 15;
  f32x4 acc[4][4] = {};
  for (int k0 = 0; k0 < K; k0 += 32) {
    bf16x8 a[4], b[4];
#pragma unroll
    for (int i = 0; i < 4; ++i)
      a[i] = *(const bf16x8*)(A + (size_t)(row0 + i * 16 + m16) * K + k0 + kl);
#pragma unroll
    for (int j = 0; j < 4; ++j)
      b[j] = *(const bf16x8*)(Bm + (size_t)(col0 + j * 16 + m16) * K + k0 + kl);
#pragma unroll
    for (int i = 0; i < 4; ++i)
#pragma unroll
      for (int j = 0; j < 4; ++j)
        acc[i][j] = __builtin_amdgcn_mfma_f32_16x16x32_bf16(a[i], b[j], acc[i][j], 0, 0, 0);
  }
  const int rsub = (lane >> 4) * 4;
#pragma unroll
  for (int i = 0; i < 4; ++i) {
    int row = row0 + i * 16 + rsub;
#pragma unroll
    for (int j = 0; j < 4; ++j) {
      int col = col0 + j * 16 + m16;
      float bv = bias[col];
#pragma unroll
      for (int r = 0; r < 4; ++r) {
        int rr = row + r;
        int crow = REMAP ? ((rr >> TCL2) * S_ + t0 + (rr & (TC_ - 1))) : rr;
        C[(size_t)crow * N + col] = acc[i][j][r] + bv;
      }
    }
  }
}

// ---------------------------------------------------------------------------
// One GRU chain (one layer, one chunk) on 256 blocks; round-9 protocol.
// ---------------------------------------------------------------------------
__device__ __forceinline__ void chain_scan(const ChainArgs& ca, const float* __restrict__ h0,
                                           float* __restrict__ hid_out, char* smem, int bx) {
  char* stage = smem + STAGE_OFF;
  float* h_own = (float*)(smem + HOWN_OFF);  // [16][17]
  float* z_own = (float*)(smem + ZOWN_OFF);  // [16][17]

  const int tid = threadIdx.x;
  const int lane = tid & 63;
  const int w = tid >> 6;
  const int rg = bx >> 6;
  const int cg = bx & 63;
  const int fid = bx;
  const int rgbase = rg * 64;
  const int m16 = lane & 15;
  const int kl = (lane >> 4) * 8;
  const int rsub = (lane >> 4) * 4;
  const int swzA = (m16 & 7) << 4;

  const float* xp = ca.xp;
  const __hip_bfloat16* Wh = ca.Wh;
  u32* hbuf = ca.hbuf;
  u32* rhbuf = ca.rhbuf;
  u32* flagA = ca.fA;
  u32* flagB = ca.fB;
  const u32 baseA = ca.baseA, baseB = ca.baseB;
  const int t0 = ca.t0, layer = ca.layer;

  // anti-phase stagger: offset this chain's rendezvous cadence vs the peer
  // chain co-resident on the same CU (converts lock-phase contention into
  // latency hiding). ~6 us = half a step.
  for (int i = 0; i < ca.stagger; ++i) __builtin_amdgcn_s_sleep(16);

  // ---- init: h_own; publish h(-1) into hbuf parity1 at t0==0 ----
  {
    int row = tid >> 3, pp = tid & 7;  // 16 rows x 8 pairs
    int col = cg * 16 + pp * 2;
    int grow = rg * 16 + row;
    float v0, v1;
    if (t0 == 0) {
      v0 = h0[((size_t)grow * 2 + layer) * H_ + col];
      v1 = h0[((size_t)grow * 2 + layer) * H_ + col + 1];
      coh_st(hbuf + EXN + (((size_t)(cg * 4 + rg) * 16 + row) * 8 + pp),
             f2bf_bits(v0) | (f2bf_bits(v1) << 16));
    } else {
      v0 = ca.hf[grow * H_ + col];
      v1 = ca.hf[grow * H_ + col + 1];
    }
    h_own[row * 17 + pp * 2] = v0;
    h_own[row * 17 + pp * 2 + 1] = v1;
  }
  asm volatile("s_waitcnt vmcnt(0)" ::: "memory");
  __syncthreads();
  if (tid == 0) coh_st(flagB + (size_t)fid * FPAD, baseB + 1);

  for (int t = 0; t < TC_; ++t) {
    const int par = t & 1;
    const int colA = cg * 16 + m16 + ((w == 1) ? H_ : 0);
    float xpv[4], xpg[4];
#pragma unroll
    for (int j = 0; j < 4; ++j) {
      int grow = rg * 16 + rsub + j;
      xpv[j] = xp[((size_t)(grow * TC_ + t)) * H3_ + colA];
    }
    if (w == 0) {
#pragma unroll
      for (int j = 0; j < 4; ++j) {
        int grow = rg * 16 + rsub + j;
        xpg[j] = xp[((size_t)(grow * TC_ + t)) * H3_ + 2 * H_ + cg * 16 + m16];
      }
    }

    // ================= phase A =================
    waitflags(flagB, rgbase, baseB + 1 + t);
    stage_ex(hbuf + (par ^ 1) * EXN, stage, tid, rg);
    __syncthreads();
    {
      f32x4 acc0 = {}, acc1 = {};
      const char* abase = stage + m16 * 2048;
      const __hip_bfloat16* Bb = Wh + (size_t)colA * H_;
#pragma unroll
      for (int k0 = 0; k0 < H_; k0 += 64) {
        bf16x8 a0 = *(const bf16x8*)(abase + (((k0 + kl) * 2) ^ swzA));
        bf16x8 a1 = *(const bf16x8*)(abase + (((k0 + 32 + kl) * 2) ^ swzA));
        bf16x8 b0 = *(const bf16x8*)(Bb + k0 + kl);
        bf16x8 b1 = *(const bf16x8*)(Bb + k0 + 32 + kl);
        acc0 = __builtin_amdgcn_mfma_f32_16x16x32_bf16(a0, b0, acc0, 0, 0, 0);
        acc1 = __builtin_amdgcn_mfma_f32_16x16x32_bf16(a1, b1, acc1, 0, 0, 0);
      }
      if (w == 0) {
#pragma unroll
        for (int j = 0; j < 4; ++j) {
          float pre = acc0[j] + acc1[j] + xpv[j];
          z_own[(rsub + j) * 17 + m16] = 1.f / (1.f + expf(-pre));
        }
      } else {
#pragma unroll
        for (int j = 0; j < 4; ++j) {
          int lr = rsub + j;
          float pre = acc0[j] + acc1[j] + xpv[j];
          float s = 1.f / (1.f + expf(-pre));
          float rh = s * h_own[lr * 17 + m16];
          u32 bits = f2bf_bits(rh);
          u32 pair = bits | (((u32)__shfl_down((int)bits, 1)) << 16);
          if ((m16 & 1) == 0)
            coh_st(rhbuf + par * EXN + (((size_t)(cg * 4 + rg) * 16 + lr) * 8 + (m16 >> 1)),
                   pair);
        }
        asm volatile("s_waitcnt vmcnt(0)" ::: "memory");
      }
    }
    __syncthreads();
    if (tid == 0) coh_st(flagA + (size_t)fid * FPAD, baseA + t + 1);

    // ================= phase B =================
    waitflags(flagA, rgbase, baseA + t + 1);
    stage_ex(rhbuf + par * EXN, stage, tid, rg);
    __syncthreads();
    if (w == 0) {
      f32x4 acc0 = {}, acc1 = {};
      const char* abase = stage + m16 * 2048;
      const __hip_bfloat16* Bb = Wh + (size_t)(2 * H_ + cg * 16 + m16) * H_;
#pragma unroll
      for (int k0 = 0; k0 < H_; k0 += 64) {
        bf16x8 a0 = *(const bf16x8*)(abase + (((k0 + kl) * 2) ^ swzA));
        bf16x8 a1 = *(const bf16x8*)(abase + (((k0 + 32 + kl) * 2) ^ swzA));
        bf16x8 b0 = *(const bf16x8*)(Bb + k0 + kl);
        bf16x8 b1 = *(const bf16x8*)(Bb + k0 + 32 + kl);
        acc0 = __builtin_amdgcn_mfma_f32_16x16x32_bf16(a0, b0, acc0, 0, 0, 0);
        acc1 = __builtin_amdgcn_mfma_f32_16x16x32_bf16(a1, b1, acc1, 0, 0, 0);
      }
#pragma unroll
      for (int j = 0; j < 4; ++j) {
        int lr = rsub + j;
        float pre = acc0[j] + acc1[j] + xpg[j];
        float gg = tanhf(pre);
        float zz = z_own[lr * 17 + m16];
        float hv = h_own[lr * 17 + m16];
        float hn = zz * hv + (1.f - zz) * gg;
        h_own[lr * 17 + m16] = hn;
        u32 bits = f2bf_bits(hn);
        u32 pair = bits | (((u32)__shfl_down((int)bits, 1)) << 16);
        if ((m16 & 1) == 0)
          coh_st(hbuf + par * EXN + (((size_t)(cg * 4 + rg) * 16 + lr) * 8 + (m16 >> 1)), pair);
        ca.y[((size_t)((rg * 16 + lr) * TC_ + t)) * H_ + cg * 16 + m16] = __float2bfloat16(hn);
      }
      asm volatile("s_waitcnt vmcnt(0)" ::: "memory");
    }
    __syncthreads();
    if (tid == 0) coh_st(flagB + (size_t)fid * FPAD, baseB + t + 2);
  }

  // ---- persist h_own ----
  {
    int row = tid >> 3, pp = tid & 7;
    int col = cg * 16 + pp * 2;
    int grow = rg * 16 + row;
    float v0 = h_own[row * 17 + pp * 2];
    float v1 = h_own[row * 17 + pp * 2 + 1];
    ca.hf[grow * H_ + col] = v0;
    ca.hf[grow * H_ + col + 1] = v1;
    if (t0 + TC_ == S_) {
      hid_out[((size_t)grow * 2 + layer) * H_ + col] = v0;
      hid_out[((size_t)grow * 2 + layer) * H_ + col + 1] = v1;
    }
  }
}

// fused: blocks [0,256) run chain a0 (layer 0, chunk c);
//        blocks [256,512) run chain a1 (layer 1, chunk c-1).
__global__ __launch_bounds__(NTHR) void gru_scan_fused(ChainArgs a0, ChainArgs a1,
                                                       const float* __restrict__ h0,
                                                       float* __restrict__ hid_out) {
  extern __shared__ char smem[];
  if (blockIdx.x < 256) {
    if (!a0.active) return;
    chain_scan(a0, h0, hid_out, smem, blockIdx.x);
  } else {
    if (!a1.active) return;
    chain_scan(a1, h0, hid_out, smem, blockIdx.x - 256);
  }
}

// ---------------------------------------------------------------------------
extern "C" void kernel_launch(void* const* d_in, const int* in_sizes, int n_in,
                              void* d_out, int out_size, void* d_ws, size_t ws_size,
                              hipStream_t stream) {
  const float* x   = (const float*)d_in[0];
  const float* h0  = (const float*)d_in[1];
  const float* Wx0 = (const float*)d_in[2];
  const float* Wh0 = (const float*)d_in[3];
  const float* bh0 = (const float*)d_in[4];
  const float* Wx1 = (const float*)d_in[5];
  const float* Wh1 = (const float*)d_in[6];
  const float* bh1 = (const float*)d_in[7];
  const float* Why = (const float*)d_in[8];
  const float* by  = (const float*)d_in[9];
  float* out = (float*)d_out;
  float* hid_out = out + (size_t)NROW * OUT_;

  (void)hipFuncSetAttribute((const void*)gru_scan_fused,
                            hipFuncAttributeMaxDynamicSharedMemorySize, SMEM_BYTES);

  char* ws = (char*)d_ws;
  size_t off = 0;
  auto alloc = [&](size_t bytes) {
    char* p = ws + off;
    off += (bytes + 255) & ~(size_t)255;
    return p;
  };
  __hip_bfloat16* wx0b = (__hip_bfloat16*)alloc((size_t)H3_ * IN_ * 2);
  __hip_bfloat16* wh0b = (__hip_bfloat16*)alloc((size_t)H3_ * H_ * 2);
  __hip_bfloat16* wx1b = (__hip_bfloat16*)alloc((size_t)H3_ * H_ * 2);
  __hip_bfloat16* wh1b = (__hip_bfloat16*)alloc((size_t)H3_ * H_ * 2);
  __hip_bfloat16* whyb = (__hip_bfloat16*)alloc((size_t)OUT_ * H_ * 2);
  float* h_f32_0 = (float*)alloc((size_t)B_ * H_ * 4);
  float* h_f32_1 = (float*)alloc((size_t)B_ * H_ * 4);
  u32* hbuf_0  = (u32*)alloc((size_t)2 * EXN * 4);
  u32* hbuf_1  = (u32*)alloc((size_t)2 * EXN * 4);
  u32* rhbuf_0 = (u32*)alloc((size_t)2 * EXN * 4);
  u32* rhbuf_1 = (u32*)alloc((size_t)2 * EXN * 4);
  __hip_bfloat16* x_bfc = (__hip_bfloat16*)alloc((size_t)MC_ * IN_ * 2);
  __hip_bfloat16* y0buf = (__hip_bfloat16*)alloc((size_t)MC_ * H_ * 2);
  __hip_bfloat16* y1buf = (__hip_bfloat16*)alloc((size_t)MC_ * H_ * 2);
  float* xp0buf = (float*)alloc((size_t)MC_ * H3_ * 4);
  float* xp1buf = (float*)alloc((size_t)MC_ * H3_ * 4);
  u32* flags    = (u32*)alloc(4 * 256 * FPAD * 4);  // 64KB, 1 line/flag
  (void)ws_size;

  (void)hipMemsetAsync(flags, 0, 4 * 256 * FPAD * 4, stream);

  auto cast = [&](const float* in, __hip_bfloat16* o, size_t n) {
    cast_f32_to_bf16<<<dim3((unsigned)((n / 4 + 255) / 256)), dim3(256), 0, stream>>>(in, o,
                                                                                     (int)(n / 4));
  };
  cast(Wx0, wx0b, (size_t)H3_ * IN_);
  cast(Wh0, wh0b, (size_t)H3_ * H_);
  cast(Wx1, wx1b, (size_t)H3_ * H_);
  cast(Wh1, wh1b, (size_t)H3_ * H_);
  cast(Why, whyb, (size_t)OUT_ * H_);

  u32* fA0 = flags;
  u32* fB0 = flags + 256 * FPAD;
  u32* fA1 = flags + 512 * FPAD;
  u32* fB1 = flags + 768 * FPAD;

  auto mkchain = [&](int layer, int chunk, int active) {
    ChainArgs ca;
    int cc = chunk < 0 ? 0 : chunk;
    ca.xp = layer == 0 ? xp0buf : xp1buf;
    ca.Wh = layer == 0 ? wh0b : wh1b;
    ca.hf = layer == 0 ? h_f32_0 : h_f32_1;
    ca.hbuf = layer == 0 ? hbuf_0 : hbuf_1;
    ca.rhbuf = layer == 0 ? rhbuf_0 : rhbuf_1;
    ca.fA = layer == 0 ? fA0 : fA1;
    ca.fB = layer == 0 ? fB0 : fB1;
    ca.y = layer == 0 ? y0buf : y1buf;
    ca.baseA = (u32)cc * TC_;
    ca.baseB = (u32)cc * (TC_ + 1);
    ca.t0 = cc * TC_;
    ca.layer = layer;
    ca.active = active;
    ca.stagger = (layer == 1) ? 14 : 0;  // ~6 us anti-phase offset
    return ca;
  };

  // prologue
  gather_cast_x<<<dim3(MC_ * IN_ / 4 / 256), dim3(256), 0, stream>>>(x, x_bfc, 0);
  gemm_nt_bias<false><<<dim3(H3_ / 128, MC_ / 128), dim3(256), 0, stream>>>(
      x_bfc, wx0b, bh0, xp0buf, MC_, H3_, IN_, 0);

  for (int c = 0; c <= NCHUNK; ++c) {
    ChainArgs a0 = mkchain(0, c, c < NCHUNK ? 1 : 0);
    ChainArgs a1 = mkchain(1, c - 1, c > 0 ? 1 : 0);
    {
      void* args[] = {(void*)&a0, (void*)&a1, (void*)&h0, (void*)&hid_out};
      hipError_t e = hipLaunchCooperativeKernel((void*)gru_scan_fused, dim3(NBLK), dim3(NTHR),
                                                args, SMEM_BYTES, stream);
      if (e != hipSuccess) {
        (void)hipGetLastError();  // clear sticky error
        gru_scan_fused<<<dim3(NBLK), dim3(NTHR), SMEM_BYTES, stream>>>(a0, a1, h0, hid_out);
      }
    }
    if (c < NCHUNK) {
      // xp1 for layer-1 chunk c (consumed by fused(c+1))
      gemm_nt_bias<false><<<dim3(H3_ / 128, MC_ / 128), dim3(256), 0, stream>>>(
          y0buf, wx1b, bh1, xp1buf, MC_, H3_, H_, 0);
    }
    if (c + 1 < NCHUNK) {
      // xp0 for layer-0 chunk c+1 (consumed by fused(c+1))
      gather_cast_x<<<dim3(MC_ * IN_ / 4 / 256), dim3(256), 0, stream>>>(x, x_bfc, (c + 1) * TC_);
      gemm_nt_bias<false><<<dim3(H3_ / 128, MC_ / 128), dim3(256), 0, stream>>>(
          x_bfc, wx0b, bh0, xp0buf, MC_, H3_, IN_, 0);
    }
    if (c > 0) {
      // output projection for layer-1 chunk c-1 (y1buf just produced)
      gemm_nt_bias<true><<<dim3(OUT_ / 128, MC_ / 128), dim3(256), 0, stream>>>(
          y1buf, whyb, by, out, MC_, OUT_, H_, (c - 1) * TC_);
    }
  }
}